// Round 1
// baseline (290.026 us; speedup 1.0000x reference)
//
#include <hip/hip_runtime.h>

#define BATCH 8
#define HH 64
#define WW 64
#define CC 256
#define KK 512
#define CH 7
#define CW 7
#define HW 4096            // HH*WW
#define CROPS_ELEMS (BATCH * KK * CH * CW * CC)   // 51,380,224
#define BOXES_ELEMS (BATCH * KK * 4)              // 16,384

using f4 = __attribute__((ext_vector_type(4))) float;

// ---------------------------------------------------------------------------
// Kernel 1 (unchanged): per-batch top-512 by RANK SELECTION.
// key = (ordered_uint(score) << 12) | (4095 - index) is unique per element, so
// rank(i) = #{keys > key_i} is the exact descending-sort position with
// jax.lax.top_k tie semantics (equal score -> lower index first).
// ---------------------------------------------------------------------------
__global__ __launch_bounds__(256) void rank_topk_kernel(
    const float* __restrict__ scores,      // [B, 4096]
    const float* __restrict__ boxes,       // [B, 4096, 4]
    float* __restrict__ boxes_out,         // [B, 512, 4]
    float* __restrict__ idx_out)           // [B, 512] (as float values)
{
    __shared__ unsigned long long keys[HW];   // 32 KB
    __shared__ int cnt[64];

    const int b     = blockIdx.x & 7;         // batch -> XCD
    const int chunk = blockIdx.x >> 3;        // which 64-element slice we rank
    const int tid   = threadIdx.x;

    for (int i = tid; i < HW; i += 256) {
        unsigned int u = __float_as_uint(scores[b * HW + i]);
        u = (u & 0x80000000u) ? ~u : (u | 0x80000000u);
        keys[i] = ((unsigned long long)u << 12) |
                  (unsigned long long)(HW - 1 - i);
    }
    if (tid < 64) cnt[tid] = 0;
    __syncthreads();

    const int e_local = tid & 63;
    const int e       = chunk * 64 + e_local;
    const unsigned long long mine = keys[e];
    const int seg = (tid >> 6) * (HW / 4);

    int c = 0;
    #pragma unroll 8
    for (int j = 0; j < HW / 4; ++j) {
        c += (keys[seg + j] > mine) ? 1 : 0;
    }
    atomicAdd(&cnt[e_local], c);
    __syncthreads();

    if (tid < 64) {
        const int r = cnt[tid];                 // exact descending rank
        if (r < KK) {
            const int i = chunk * 64 + tid;     // original flat index
            idx_out[b * KK + r] = (float)i;
            const float* bp = boxes + (size_t)(b * HW + i) * 4;
            float* op = boxes_out + (size_t)(b * KK + r) * 4;
            op[0] = bp[0]; op[1] = bp[1]; op[2] = bp[2]; op[3] = bp[3];
        }
    }
}

// ---------------------------------------------------------------------------
// Kernel 2 v2: crop_and_resize, ONE WAVE PER ROI (49 pixels), lane owns 4 ch.
//
// Why (theory): the previous one-wave-per-pixel version launched 50,176
// 4-wave workgroups, each wave re-loading its box (49x redundant), redoing
// the full coordinate chain per pixel, and exposing gather latency with only
// 4 loads of MLP before dying. It ran ~3x above its ~40 µs roofline
// (205 MB NT writes + 822 MB L2-resident gathers).
//
// This version: 1024 blocks (8 batches x 128), 4 waves/block, wave = (b, n).
//  - box read once per wave; x-corner byte-offsets + weights precomputed into
//    registers (fully-unrolled constant-index tables — no scratch);
//  - y-corner math redone per row (7 iterations, ~12 VALU each — cheap and
//    avoids runtime-indexed arrays);
//  - inner ix row fully unrolled: ~28 independent 1 KiB gathers in flight;
//  - 49 KiB of output per wave is a single contiguous NT-store stream.
// __launch_bounds__(256,4) caps VGPR at 128 so exactly 4 blocks/CU fit
// (grid = 1024 = 4 * 256 CUs, zero remainder).
//
// XCD swizzle kept: batch = blockIdx & 7, so each XCD's gathers stay inside
// its batch's 4.19 MB fm slice (fits that XCD's 4 MB L2; NT stores don't
// evict it).
//
// Coordinate math mirrors the reference's elementwise rounding exactly (no
// FMA contraction in the coordinate chain): floor() boundaries are
// discontinuous under the clip-after-floor edge semantics.
// ---------------------------------------------------------------------------
__global__ __launch_bounds__(256, 4) void crops_kernel(
    const float* __restrict__ fm,          // [B, 64, 64, 256]
    const float* __restrict__ sboxes,      // [B, 512, 4]
    float* __restrict__ out)               // [B, 512, 7, 7, 256]
{
    const int b    = blockIdx.x & 7;                       // batch -> XCD
    const int n    = (blockIdx.x >> 3) * 4 + (threadIdx.x >> 6);  // roi 0..511
    const int lane = threadIdx.x & 63;
    const int bn   = b * KK + n;

    const float* bp = sboxes + (size_t)bn * 4;
    const float y1 = bp[0], x1 = bp[1], y2 = bp[2], x2 = bp[3];

    // Per-column corner offsets (in floats) + weights. Fully unrolled writes
    // and reads -> promoted to registers (rule: no runtime-indexed arrays).
    int   xo0[CW], xo1[CW];
    float wxa[CW];
    #pragma unroll
    for (int ix = 0; ix < CW; ++ix) {
        const float f = (float)ix / 6.0f;
        const float x = __fmul_rn(__fadd_rn(x1, __fmul_rn(f, __fsub_rn(x2, x1))), 63.0f);
        const float x0f = floorf(x);
        wxa[ix] = x - x0f;
        int x0 = (int)x0f; x0 = min(max(x0, 0), WW - 1);
        xo0[ix] = x0 * CC;
        xo1[ix] = min(x0 + 1, WW - 1) * CC;
    }

    const float* fb = fm + (size_t)b * (HH * WW * CC) + lane * 4;
    float* op = out + (size_t)bn * (CH * CW * CC) + lane * 4;

    for (int iy = 0; iy < CH; ++iy) {
        const float f = (float)iy / 6.0f;
        const float y = __fmul_rn(__fadd_rn(y1, __fmul_rn(f, __fsub_rn(y2, y1))), 63.0f);
        const float y0f = floorf(y);
        const float wy  = y - y0f;
        const float owy = 1.0f - wy;
        int y0 = (int)y0f; y0 = min(max(y0, 0), HH - 1);
        const int y1i = min(y0 + 1, HH - 1);
        const float* py0 = fb + y0  * (WW * CC);
        const float* py1 = fb + y1i * (WW * CC);

        #pragma unroll
        for (int ix = 0; ix < CW; ++ix) {
            const f4 v00 = *(const f4*)(py0 + xo0[ix]);
            const f4 v01 = *(const f4*)(py0 + xo1[ix]);
            const f4 v10 = *(const f4*)(py1 + xo0[ix]);
            const f4 v11 = *(const f4*)(py1 + xo1[ix]);
            const float wx = wxa[ix], owx = 1.0f - wx;

            f4 r;
            #pragma unroll
            for (int k = 0; k < 4; ++k) {
                float t  = v00[k] * owx + v01[k] * wx;
                float bo = v10[k] * owx + v11[k] * wx;
                r[k] = t * owy + bo * wy;
            }
            __builtin_nontemporal_store(r, (f4*)op);
            op += CC;
        }
    }
}

extern "C" void kernel_launch(void* const* d_in, const int* in_sizes, int n_in,
                              void* d_out, int out_size, void* d_ws, size_t ws_size,
                              hipStream_t stream) {
    const float* feature_map = (const float*)d_in[0];   // 8*64*64*256
    const float* boxes       = (const float*)d_in[1];   // 8*64*64*4
    const float* rpn_loss    = (const float*)d_in[2];   // 8*64*64

    float* crops_out = (float*)d_out;                       // 51,380,224
    float* boxes_out = crops_out + CROPS_ELEMS;             // 16,384
    float* idx_out   = boxes_out + BOXES_ELEMS;             // 4,096

    rank_topk_kernel<<<BATCH * 64, 256, 0, stream>>>(rpn_loss, boxes, boxes_out, idx_out);

    // 8 batches * 128 blocks; each block = 4 waves = 4 ROIs.
    crops_kernel<<<BATCH * (KK / 4), 256, 0, stream>>>(feature_map, boxes_out, crops_out);
}

// Round 2
// 276.121 us; speedup vs baseline: 1.0504x; 1.0504x over previous
//
#include <hip/hip_runtime.h>

#define BATCH 8
#define HH 64
#define WW 64
#define CC 256
#define KK 512
#define CH 7
#define CW 7
#define HW 4096            // HH*WW
#define CROPS_ELEMS (BATCH * KK * CH * CW * CC)   // 51,380,224
#define BOXES_ELEMS (BATCH * KK * 4)              // 16,384

using f4 = __attribute__((ext_vector_type(4))) float;

// ---------------------------------------------------------------------------
// Kernel 1 (unchanged): per-batch top-512 by RANK SELECTION.
// key = (ordered_uint(score) << 12) | (4095 - index) is unique per element, so
// rank(i) = #{keys > key_i} is the exact descending-sort position with
// jax.lax.top_k tie semantics (equal score -> lower index first).
// ---------------------------------------------------------------------------
__global__ __launch_bounds__(256) void rank_topk_kernel(
    const float* __restrict__ scores,      // [B, 4096]
    const float* __restrict__ boxes,       // [B, 4096, 4]
    float* __restrict__ boxes_out,         // [B, 512, 4]
    float* __restrict__ idx_out)           // [B, 512] (as float values)
{
    __shared__ unsigned long long keys[HW];   // 32 KB
    __shared__ int cnt[64];

    const int b     = blockIdx.x & 7;         // batch -> XCD
    const int chunk = blockIdx.x >> 3;        // which 64-element slice we rank
    const int tid   = threadIdx.x;

    for (int i = tid; i < HW; i += 256) {
        unsigned int u = __float_as_uint(scores[b * HW + i]);
        u = (u & 0x80000000u) ? ~u : (u | 0x80000000u);
        keys[i] = ((unsigned long long)u << 12) |
                  (unsigned long long)(HW - 1 - i);
    }
    if (tid < 64) cnt[tid] = 0;
    __syncthreads();

    const int e_local = tid & 63;
    const int e       = chunk * 64 + e_local;
    const unsigned long long mine = keys[e];
    const int seg = (tid >> 6) * (HW / 4);

    int c = 0;
    #pragma unroll 8
    for (int j = 0; j < HW / 4; ++j) {
        c += (keys[seg + j] > mine) ? 1 : 0;
    }
    atomicAdd(&cnt[e_local], c);
    __syncthreads();

    if (tid < 64) {
        const int r = cnt[tid];                 // exact descending rank
        if (r < KK) {
            const int i = chunk * 64 + tid;     // original flat index
            idx_out[b * KK + r] = (float)i;
            const float* bp = boxes + (size_t)(b * HW + i) * 4;
            float* op = boxes_out + (size_t)(b * KK + r) * 4;
            op[0] = bp[0]; op[1] = bp[1]; op[2] = bp[2]; op[3] = bp[3];
        }
    }
}

// ---------------------------------------------------------------------------
// Kernel 2 (v3): crop_and_resize — REVERT to one-wave-per-pixel (v1 structure;
// the ROI-per-wave v2 regressed ~19 µs: fewer waves/CU + VGPR-capped MLP).
//
// ONE variable changed vs v1: the output store is now inline-asm
//   global_store_dwordx4 ... sc0 sc1 nt
// sc1 = system-scope store -> bypasses the XCD L2 entirely (CDNA streaming-
// store idiom); nt = evict-first at the MALL. Rationale: plain
// __builtin_nontemporal_store still ALLOCATES in L2, so the 205.6 MB output
// stream continuously evicted the XCD-pinned 4.19 MB fm slice (a marginal fit
// in the 4.0 MiB L2), pushing the 822 MB of corner gathers down to Infinity
// Cache. With stores bypassing L2, fm stays resident and gathers are L2 hits.
//
// XCD swizzle: batch = blockIdx % 8, so each XCD's gathers stay inside its
// batch's fm slice.
//
// Coordinate math mirrors the reference's elementwise rounding exactly (no
// FMA contraction): floor() boundaries are discontinuous under the
// clip-after-floor edge semantics.
// ---------------------------------------------------------------------------
__global__ __launch_bounds__(256) void crops_kernel(
    const float* __restrict__ fm,          // [B, 64, 64, 256]
    const float* __restrict__ sboxes,      // [B, 512, 4]
    float* __restrict__ out)               // [B, 512, 7, 7, 256]
{
    const int b     = blockIdx.x & 7;              // batch -> XCD
    const int inner = blockIdx.x >> 3;             // 0..6271 within batch
    const int wib   = inner * 4 + (threadIdx.x >> 6);  // wave-in-batch: 0..25087
    const int lane  = threadIdx.x & 63;

    const int q  = wib % 49;               // iy*7 + ix
    const int n  = wib / 49;               // roi within batch
    const int iy = q / 7;
    const int ix = q % 7;
    const int bn = b * KK + n;

    const float* bp = sboxes + (size_t)bn * 4;
    const float y1 = bp[0], x1 = bp[1], y2 = bp[2], x2 = bp[3];

    const float fy = (float)iy / 6.0f;
    const float fx = (float)ix / 6.0f;
    // y = (y1 + fy*(y2-y1)) * 63 — exact elementwise rounding, no contraction
    const float y = __fmul_rn(__fadd_rn(y1, __fmul_rn(fy, __fsub_rn(y2, y1))), 63.0f);
    const float x = __fmul_rn(__fadd_rn(x1, __fmul_rn(fx, __fsub_rn(x2, x1))), 63.0f);

    const float y0f = floorf(y);
    const float x0f = floorf(x);
    const float wy = y - y0f;
    const float wx = x - x0f;

    int y0 = (int)y0f; y0 = min(max(y0, 0), HH - 1);
    int x0 = (int)x0f; x0 = min(max(x0, 0), WW - 1);
    const int y1i = min(y0 + 1, HH - 1);
    const int x1i = min(x0 + 1, WW - 1);

    const size_t base = (size_t)b * (HH * WW * CC);
    const int c0 = lane * 4;
    const f4 v00 = *(const f4*)(fm + base + (size_t)(y0  * WW + x0 ) * CC + c0);
    const f4 v01 = *(const f4*)(fm + base + (size_t)(y0  * WW + x1i) * CC + c0);
    const f4 v10 = *(const f4*)(fm + base + (size_t)(y1i * WW + x0 ) * CC + c0);
    const f4 v11 = *(const f4*)(fm + base + (size_t)(y1i * WW + x1i) * CC + c0);

    const float owx = 1.0f - wx;
    const float owy = 1.0f - wy;

    f4 r;
    #pragma unroll
    for (int k = 0; k < 4; ++k) {
        float t  = v00[k] * owx + v01[k] * wx;
        float bo = v10[k] * owx + v11[k] * wx;
        r[k] = t * owy + bo * wy;
    }

    // Streaming store: system-scope (sc1) bypasses the XCD L2 so the output
    // stream can't evict the L2-resident fm slice; nt = evict-first at MALL.
    float* optr = out + (size_t)(bn * 49 + q) * CC + c0;
    asm volatile("global_store_dwordx4 %0, %1, off sc0 sc1 nt"
                 :: "v"(optr), "v"(r) : "memory");
}

extern "C" void kernel_launch(void* const* d_in, const int* in_sizes, int n_in,
                              void* d_out, int out_size, void* d_ws, size_t ws_size,
                              hipStream_t stream) {
    const float* feature_map = (const float*)d_in[0];   // 8*64*64*256
    const float* boxes       = (const float*)d_in[1];   // 8*64*64*4
    const float* rpn_loss    = (const float*)d_in[2];   // 8*64*64

    float* crops_out = (float*)d_out;                       // 51,380,224
    float* boxes_out = crops_out + CROPS_ELEMS;             // 16,384
    float* idx_out   = boxes_out + BOXES_ELEMS;             // 4,096

    rank_topk_kernel<<<BATCH * 64, 256, 0, stream>>>(rpn_loss, boxes, boxes_out, idx_out);

    const int total_waves  = BATCH * KK * CH * CW;          // 200,704
    const int blocks       = total_waves / 4;               // 50,176 (256 thr = 4 waves)
    crops_kernel<<<blocks, 256, 0, stream>>>(feature_map, boxes_out, crops_out);
}